// Round 2
// baseline (7795.026 us; speedup 1.0000x reference)
//
#include <hip/hip_runtime.h>
#include <hip/hip_fp16.h>
#include <math.h>

// Problem constants
#define B_  4096
#define L_  60
#define I_  13
#define H_  128
#define G4  512           // 4*H gates

#define S0   (141*512)    // 72192  floats (layer0 wT: K=13+128)
#define S12  (384*512)    // 196608 floats (layers1/2 wT: K=256+128)
#define WTOT (2*S0 + 4*S12)   // 930816 floats

// ---------------------------------------------------------------------------
// Prep: wT[k][g] = (k<KIN) ? w_ih[g][k] : w_hh[g][k-KIN];  bias[g]=b_ih+b_hh
// ---------------------------------------------------------------------------
__global__ void prep_kernel(const float* __restrict__ wih, const float* __restrict__ whh,
                            const float* __restrict__ bih, const float* __restrict__ bhh,
                            float* __restrict__ wT, float* __restrict__ bias, int KIN) {
    int K = KIN + H_;
    int n = K * G4;
    for (int e = blockIdx.x * blockDim.x + threadIdx.x; e < n; e += gridDim.x * blockDim.x) {
        int k = e >> 9, g = e & 511;
        wT[e] = (k < KIN) ? wih[g * KIN + k] : whh[g * H_ + (k - KIN)];
        if (e < G4) bias[e] = bih[e] + bhh[e];
    }
}

__device__ __forceinline__ float sigm(float x) { return 1.f / (1.f + __expf(-x)); }
// tanh via exp, safe at +/-inf: 1 - 2/(e^{2x}+1)
__device__ __forceinline__ float tanh_f(float x) { return 1.f - 2.f / (__expf(2.f * x) + 1.f); }

// ---------------------------------------------------------------------------
// Fused per-layer BiLSTM kernel. grid = 2*(rows/32) blocks (dir = bit 0),
// 256 threads. Each block owns 32 batch rows for one direction, iterates all
// 60 timesteps. LDS holds A^T = [x_t rows (KIN); h rows (128)] x 32 (+pad).
// Thread tile: 8 rows x 2 h-cols x 4 gate types = 64 fp32 accumulators; the
// LSTM pointwise runs fully in registers (c state also in registers).
// Input dtype TI is float (layer 0) or __half (layers 1-2); output is __half.
// ---------------------------------------------------------------------------
template <typename TI, int KIN>
__global__ __launch_bounds__(256)
void lstm_layer(const TI* __restrict__ in,             // [rows][L][KIN]
                const float* __restrict__ wT_f, const float* __restrict__ wT_b,
                const float* __restrict__ bias_f, const float* __restrict__ bias_b,
                __half* __restrict__ out)              // [rows][L][256]
{
    constexpr int K    = KIN + H_;
    constexpr int BT   = 32;
    constexpr int ROWP = BT + 4;   // 36 floats: rows stay 16B-aligned, breaks pow2 stride

    __shared__ __align__(16) float aT[K * ROWP];

    const int tid   = threadIdx.x;
    const int dir   = blockIdx.x & 1;
    const int tile  = blockIdx.x >> 1;
    const int rb    = tile * BT;

    const float* __restrict__ wT   = dir ? wT_b   : wT_f;
    const float* __restrict__ bias = dir ? bias_b : bias_f;

    const int hj0 = (tid & 63) * 2;   // 2 h-columns per thread (wave spans all 128)
    const int r0  = (tid >> 6) * 8;   // 8 rows per thread (one rowgroup per wave)

    // zero h-rows of A^T
    for (int e = tid; e < H_ * ROWP; e += 256) aT[KIN * ROWP + e] = 0.f;

    float c[8][2];
#pragma unroll
    for (int rr = 0; rr < 8; ++rr) { c[rr][0] = 0.f; c[rr][1] = 0.f; }

    float bi[2][4];
#pragma unroll
    for (int j = 0; j < 2; ++j)
#pragma unroll
        for (int tq = 0; tq < 4; ++tq) bi[j][tq] = bias[tq * H_ + hj0 + j];

    for (int s = 0; s < L_; ++s) {
        const int t = dir ? (L_ - 1 - s) : s;

        __syncthreads();  // prev GEMM done reading aT-x; prev h-writes ordered

        // stage x_t tile (coalesced global read, transposed LDS write)
        const TI* __restrict__ inb = in + (size_t)rb * (L_ * KIN) + (size_t)t * KIN;
        for (int e = tid; e < KIN * BT; e += 256) {
            int r = e / KIN, i = e - r * KIN;
            aT[i * ROWP + r] = (float)inb[(size_t)r * (L_ * KIN) + i];
        }
        __syncthreads();

        // gates[r][g] = bias + sum_k A^T[k][r] * wT[k][g]
        float acc[8][2][4];
#pragma unroll
        for (int rr = 0; rr < 8; ++rr)
#pragma unroll
            for (int j = 0; j < 2; ++j)
#pragma unroll
                for (int tq = 0; tq < 4; ++tq) acc[rr][j][tq] = bi[j][tq];

#pragma unroll 4
        for (int k = 0; k < K; ++k) {
            const float4 a0 = *reinterpret_cast<const float4*>(&aT[k * ROWP + r0]);
            const float4 a1 = *reinterpret_cast<const float4*>(&aT[k * ROWP + r0 + 4]);
            const float* __restrict__ wrow = wT + (size_t)k * G4;
            const float2 w0 = *reinterpret_cast<const float2*>(wrow + hj0);
            const float2 w1 = *reinterpret_cast<const float2*>(wrow + H_ + hj0);
            const float2 w2 = *reinterpret_cast<const float2*>(wrow + 2 * H_ + hj0);
            const float2 w3 = *reinterpret_cast<const float2*>(wrow + 3 * H_ + hj0);
            const float av[8] = {a0.x, a0.y, a0.z, a0.w, a1.x, a1.y, a1.z, a1.w};
#pragma unroll
            for (int rr = 0; rr < 8; ++rr) {
                acc[rr][0][0] += av[rr] * w0.x;  acc[rr][1][0] += av[rr] * w0.y;
                acc[rr][0][1] += av[rr] * w1.x;  acc[rr][1][1] += av[rr] * w1.y;
                acc[rr][0][2] += av[rr] * w2.x;  acc[rr][1][2] += av[rr] * w2.y;
                acc[rr][0][3] += av[rr] * w3.x;  acc[rr][1][3] += av[rr] * w3.y;
            }
        }

        // pointwise LSTM cell (i,f,g,o PyTorch order), all in registers
#pragma unroll
        for (int rr = 0; rr < 8; ++rr) {
            float h2[2];
#pragma unroll
            for (int j = 0; j < 2; ++j) {
                const float si = sigm(acc[rr][j][0]);
                const float sf = sigm(acc[rr][j][1]);
                const float tg = tanh_f(acc[rr][j][2]);
                const float so = sigm(acc[rr][j][3]);
                const float cc = sf * c[rr][j] + si * tg;
                c[rr][j] = cc;
                h2[j] = so * tanh_f(cc);
                aT[(KIN + hj0 + j) * ROWP + (r0 + rr)] = h2[j];  // feed next step
            }
            const size_t oidx = (size_t)(rb + r0 + rr) * (L_ * 256) + (size_t)t * 256 + dir * H_ + hj0;
            *reinterpret_cast<__half2*>(&out[oidx]) = __floats2half2_rn(h2[0], h2[1]);
        }
    }
}

// ---------------------------------------------------------------------------
// Final: out[b][o] = b_out[o] + sum relu(y3[b][:]) * w_out[o][:]
// One wave per batch row; per iter each lane handles 4 halfs (two __half2).
// ---------------------------------------------------------------------------
__global__ __launch_bounds__(256)
void final_kernel(const __half* __restrict__ y, const float* __restrict__ wout,
                  const float* __restrict__ bout, float* __restrict__ outp, int nrows) {
    const int wid  = (blockIdx.x * blockDim.x + threadIdx.x) >> 6;  // local batch row
    const int lane = threadIdx.x & 63;
    if (wid >= nrows) return;
    const __half2* __restrict__ y2  = reinterpret_cast<const __half2*>(y + (size_t)wid * 15360);
    const float4*  __restrict__ w4a = reinterpret_cast<const float4*>(wout);
    const float4*  __restrict__ w4b = reinterpret_cast<const float4*>(wout + 15360);
    float s0 = 0.f, s1 = 0.f;
#pragma unroll 4
    for (int it = 0; it < 60; ++it) {
        const int p2 = it * 128 + lane * 2;          // __half2 index
        const __half2 h0 = y2[p2];
        const __half2 h1 = y2[p2 + 1];
        float4 v = make_float4(__low2float(h0), __high2float(h0),
                               __low2float(h1), __high2float(h1));
        v.x = fmaxf(v.x, 0.f); v.y = fmaxf(v.y, 0.f); v.z = fmaxf(v.z, 0.f); v.w = fmaxf(v.w, 0.f);
        const int wi = it * 64 + lane;               // float4 index (same elements)
        const float4 a = w4a[wi];
        const float4 b = w4b[wi];
        s0 += v.x * a.x + v.y * a.y + v.z * a.z + v.w * a.w;
        s1 += v.x * b.x + v.y * b.y + v.z * b.z + v.w * b.w;
    }
#pragma unroll
    for (int off = 32; off > 0; off >>= 1) {
        s0 += __shfl_down(s0, off);
        s1 += __shfl_down(s1, off);
    }
    if (lane == 0) {
        outp[wid * 2 + 0] = s0 + bout[0];
        outp[wid * 2 + 1] = s1 + bout[1];
    }
}

// ---------------------------------------------------------------------------
extern "C" void kernel_launch(void* const* d_in, const int* in_sizes, int n_in,
                              void* d_out, int out_size, void* d_ws, size_t ws_size,
                              hipStream_t stream) {
    const float* x = (const float*)d_in[0];
    // input index: 1 + layer*8 + dir*4 + {w_ih, w_hh, b_ih, b_hh}
    auto W = [&](int l, int d, int which) { return (const float*)d_in[1 + l * 8 + d * 4 + which]; };
    const float* w_out = (const float*)d_in[25];
    const float* b_out = (const float*)d_in[26];

    float* ws   = (float*)d_ws;
    float* wT   = ws;                       // WTOT floats
    float* bias = ws + WTOT;                // 6*512 floats (pad to 4096)
    __half* y0  = (__half*)(ws + WTOT + 4096);

    // segment offsets within wT
    const int o0f = 0, o0b = S0, o1f = 2 * S0, o1b = 2 * S0 + S12,
              o2f = 2 * S0 + 2 * S12, o2b = 2 * S0 + 3 * S12;

    // weight transpose + bias combine (runs every launch; ws is re-poisoned)
    prep_kernel<<<282, 256, 0, stream>>>(W(0,0,0), W(0,0,1), W(0,0,2), W(0,0,3), wT + o0f, bias + 0,    I_);
    prep_kernel<<<282, 256, 0, stream>>>(W(0,1,0), W(0,1,1), W(0,1,2), W(0,1,3), wT + o0b, bias + 512,  I_);
    prep_kernel<<<768, 256, 0, stream>>>(W(1,0,0), W(1,0,1), W(1,0,2), W(1,0,3), wT + o1f, bias + 1024, 256);
    prep_kernel<<<768, 256, 0, stream>>>(W(1,1,0), W(1,1,1), W(1,1,2), W(1,1,3), wT + o1b, bias + 1536, 256);
    prep_kernel<<<768, 256, 0, stream>>>(W(2,0,0), W(2,0,1), W(2,0,2), W(2,0,3), wT + o2f, bias + 2048, 256);
    prep_kernel<<<768, 256, 0, stream>>>(W(2,1,0), W(2,1,1), W(2,1,2), W(2,1,3), wT + o2b, bias + 2560, 256);

    // Pick batch chunking so 2 fp16 ping-pong buffers fit in ws.
    const size_t head_bytes = (size_t)(WTOT + 4096) * sizeof(float);
    const size_t avail_halfs = (ws_size > head_bytes) ? (ws_size - head_bytes) / sizeof(__half) : 0;
    int chunks = 1;
    while (chunks < 128 && (size_t)2 * (B_ / chunks) * (L_ * 256) > avail_halfs) chunks *= 2;
    const int CB = B_ / chunks;             // rows per chunk (multiple of 32)

    __half* yA = y0;
    __half* yB = y0 + (size_t)CB * (L_ * 256);

    for (int c = 0; c < chunks; ++c) {
        const float* xc = x + (size_t)c * CB * (L_ * I_);
        float* outc = (float*)d_out + (size_t)c * CB * 2;
        lstm_layer<float,  I_ ><<<2 * CB / 32, 256, 0, stream>>>(xc, wT + o0f, wT + o0b, bias + 0,    bias + 512,  yA);
        lstm_layer<__half, 256><<<2 * CB / 32, 256, 0, stream>>>(yA, wT + o1f, wT + o1b, bias + 1024, bias + 1536, yB);
        lstm_layer<__half, 256><<<2 * CB / 32, 256, 0, stream>>>(yB, wT + o2f, wT + o2b, bias + 2048, bias + 2560, yA);
        final_kernel<<<(CB + 3) / 4, 256, 0, stream>>>(yA, w_out, b_out, outc, CB);
    }
}

// Round 3
// 1276.048 us; speedup vs baseline: 6.1087x; 6.1087x over previous
//
#include <hip/hip_runtime.h>
#include <math.h>

// Problem constants
#define B_  4096
#define L_  60
#define I_  13
#define H_  128

typedef _Float16 half8 __attribute__((ext_vector_type(8)));
typedef _Float16 half4v __attribute__((ext_vector_type(4)));
typedef float float4v __attribute__((ext_vector_type(4)));

// ---------------------------------------------------------------------------
// Weight packing: B-fragment order for mfma_f32_16x16x32_f16.
// Consumption: frag(kt, w, ct), lane l, element j ->
//   B[k = kt*32 + (l>>4)*8 + j][n = (ct>>1)*128 + w*32 + (ct&1)*16 + (l&15)]
// Pack linear index e = (((kt*4 + w)*8 + ct)*64 + l)*8 + j.
// src is [512][Ksrc] row-major fp32 (w_ih or w_hh); zero-pad k >= Ksrc.
// ---------------------------------------------------------------------------
__global__ void pack_kernel(const float* __restrict__ src, _Float16* __restrict__ dst,
                            int Ksrc, int n,
                            const float* __restrict__ bih, const float* __restrict__ bhh,
                            float* __restrict__ bias_out) {
    int g0 = blockIdx.x * blockDim.x + threadIdx.x;
    for (int e = g0; e < n; e += gridDim.x * blockDim.x) {
        int j  = e & 7;
        int l  = (e >> 3) & 63;
        int ct = (e >> 9) & 7;
        int w  = (e >> 12) & 3;
        int kt = e >> 14;
        int nn = (ct >> 1) * 128 + w * 32 + (ct & 1) * 16 + (l & 15);
        int k  = kt * 32 + ((l >> 4) << 3) + j;
        dst[e] = (k < Ksrc) ? (_Float16)src[nn * Ksrc + k] : (_Float16)0.f;
    }
    if (bias_out && g0 < 512) bias_out[g0] = bih[g0] + bhh[g0];
}

__device__ __forceinline__ float sigm(float x) { return 1.f / (1.f + __expf(-x)); }
__device__ __forceinline__ float tanh_f(float x) { return 1.f - 2.f / (__expf(2.f * x) + 1.f); }

// LDS layout (halfs): WH pack [0,65536) ; AH h-tile [65536, 65536+32*136) ; AX0 [69888, 70912)
#define WH_OFF   0
#define AH_OFF   65536
#define AHP      136          // h-tile pitch in halfs (16B-aligned rows, spreads banks)
#define AX0_OFF  69888
#define SMEM_HALFS 70912
#define SMEM_BYTES (SMEM_HALFS * 2)   // 141824

// ---------------------------------------------------------------------------
// Persistent BiLSTM layer, MFMA f16. Block = 32 batch rows x 1 direction,
// 4 waves x 64. Wave w owns h-cols [32w, 32w+32) and all 4 gates for them:
// col-tiles ct = tq*2+u at n-base = tq*128 + w*32 + u*16. Row-tiles rt=0,1.
// K = KXT*32 (x-part, streamed from global pack) + 128 (h-part, LDS pack).
// C/D frag: row = (lane>>4)*4 + reg, col = lane&15  [guide §3, dtype-indep].
// A/B frag: dim16 = lane&15, k = (lane>>4)*8 + j.
// ---------------------------------------------------------------------------
template <int KXT, int IS_L0>
__global__ __launch_bounds__(256, 1)
void lstm_mfma(const float* __restrict__ x0, const _Float16* __restrict__ yin,
               const _Float16* __restrict__ px_f, const _Float16* __restrict__ ph_f,
               const _Float16* __restrict__ px_b, const _Float16* __restrict__ ph_b,
               const float* __restrict__ bias_f, const float* __restrict__ bias_b,
               _Float16* __restrict__ yout)
{
    extern __shared__ _Float16 sm[];
    _Float16* WH  = sm + WH_OFF;
    _Float16* AHm = sm + AH_OFF;
    _Float16* AX0 = sm + AX0_OFF;

    const int tid  = threadIdx.x;
    const int lane = tid & 63;
    const int w    = tid >> 6;
    const int dir  = blockIdx.x & 1;
    const int rb   = (blockIdx.x >> 1) * 32;
    const int m    = lane & 15;
    const int q    = lane >> 4;

    const _Float16* __restrict__ px   = dir ? px_b : px_f;
    const _Float16* __restrict__ ph   = dir ? ph_b : ph_f;
    const float*    __restrict__ bias = dir ? bias_b : bias_f;

    // Load W_hh pack into LDS (65536 halfs = 8192 half8), zero h-tile.
    {
        const half8* s8 = (const half8*)ph;
        half8* d8 = (half8*)WH;
        for (int i = tid; i < 8192; i += 256) d8[i] = s8[i];
    }
    for (int i = tid; i < 32 * AHP; i += 256) AHm[i] = (_Float16)0.f;

    // Per-thread bias for its 8 col-tiles.
    float bv[8];
#pragma unroll
    for (int ct = 0; ct < 8; ++ct)
        bv[ct] = bias[(ct >> 1) * 128 + w * 32 + (ct & 1) * 16 + m];

    float cst[2][2][4];
#pragma unroll
    for (int rt = 0; rt < 2; ++rt)
#pragma unroll
        for (int u = 0; u < 2; ++u)
#pragma unroll
            for (int r = 0; r < 4; ++r) cst[rt][u][r] = 0.f;

    for (int s = 0; s < L_; ++s) {
        const int t = dir ? (L_ - 1 - s) : s;

        if (IS_L0) {
            // Stage layer-0 x into A-frag order: entry e=(rt*512 + ln*8 + j) =
            // x[row = rt*16+(ln&15)][k = (ln>>4)*8+j], zero-padded k>=13.
            const int e  = tid * 4;
            const int j0 = e & 7;
            const int ln = (e >> 3) & 63;
            const int rt = e >> 9;
            const int row = rt * 16 + (ln & 15);
            const int kb  = ((ln >> 4) << 3) + j0;
            const float* xr = x0 + (size_t)(rb + row) * (L_ * I_) + t * I_;
            half4v tmp;
#pragma unroll
            for (int jj = 0; jj < 4; ++jj) {
                int k = kb + jj;
                tmp[jj] = (k < I_) ? (_Float16)xr[k] : (_Float16)0.f;
            }
            ((half4v*)AX0)[tid] = tmp;
        }

        __syncthreads();   // (1) AX0 staged (L0) + h(t-1)/init visible

        float4v acc[2][8];
#pragma unroll
        for (int rt = 0; rt < 2; ++rt)
#pragma unroll
            for (int ct = 0; ct < 8; ++ct) {
                float b = bv[ct];
                acc[rt][ct] = (float4v){b, b, b, b};
            }

        // ---- x-part ----
        if (IS_L0) {
            half8 a0 = *(const half8*)(AX0 + lane * 8);
            half8 a1 = *(const half8*)(AX0 + 512 + lane * 8);
            const _Float16* pxw = px + w * 4096 + lane * 8;
#pragma unroll
            for (int ct = 0; ct < 8; ++ct) {
                half8 b = *(const half8*)(pxw + ct * 512);
                acc[0][ct] = __builtin_amdgcn_mfma_f32_16x16x32_f16(a0, b, acc[0][ct], 0, 0, 0);
                acc[1][ct] = __builtin_amdgcn_mfma_f32_16x16x32_f16(a1, b, acc[1][ct], 0, 0, 0);
            }
        } else {
            // A direct from global y_in (row-major contiguous in k); double-buffered.
            const _Float16* abase = yin + (size_t)(rb + m) * 15360 + t * 256 + q * 8;
            const _Float16* pxw   = px + w * 4096 + lane * 8;
            half8 aC0, aC1, bC[8], aN0, aN1, bN[8];
            aC0 = *(const half8*)(abase);
            aC1 = *(const half8*)(abase + 16 * 15360);
#pragma unroll
            for (int ct = 0; ct < 8; ++ct) bC[ct] = *(const half8*)(pxw + ct * 512);
#pragma unroll
            for (int kt = 0; kt < KXT; ++kt) {
                if (kt + 1 < KXT) {
                    aN0 = *(const half8*)(abase + (kt + 1) * 32);
                    aN1 = *(const half8*)(abase + 16 * 15360 + (kt + 1) * 32);
#pragma unroll
                    for (int ct = 0; ct < 8; ++ct)
                        bN[ct] = *(const half8*)(pxw + (kt + 1) * 16384 + ct * 512);
                }
#pragma unroll
                for (int ct = 0; ct < 8; ++ct) {
                    acc[0][ct] = __builtin_amdgcn_mfma_f32_16x16x32_f16(aC0, bC[ct], acc[0][ct], 0, 0, 0);
                    acc[1][ct] = __builtin_amdgcn_mfma_f32_16x16x32_f16(aC1, bC[ct], acc[1][ct], 0, 0, 0);
                }
                aC0 = aN0; aC1 = aN1;
#pragma unroll
                for (int ct = 0; ct < 8; ++ct) bC[ct] = bN[ct];
            }
        }

        // ---- h-part (A from LDS h-tile, B from LDS W_hh pack) ----
#pragma unroll
        for (int kh = 0; kh < 4; ++kh) {
            half8 a0 = *(const half8*)(AHm + m * AHP + kh * 32 + q * 8);
            half8 a1 = *(const half8*)(AHm + (16 + m) * AHP + kh * 32 + q * 8);
            const _Float16* whw = WH + kh * 16384 + w * 4096 + lane * 8;
#pragma unroll
            for (int ct = 0; ct < 8; ++ct) {
                half8 b = *(const half8*)(whw + ct * 512);
                acc[0][ct] = __builtin_amdgcn_mfma_f32_16x16x32_f16(a0, b, acc[0][ct], 0, 0, 0);
                acc[1][ct] = __builtin_amdgcn_mfma_f32_16x16x32_f16(a1, b, acc[1][ct], 0, 0, 0);
            }
        }

        __syncthreads();   // (2) all LDS frag reads done -> safe to overwrite h

        // ---- pointwise LSTM cell (i,f,g,o) in registers ----
#pragma unroll
        for (int rt = 0; rt < 2; ++rt)
#pragma unroll
            for (int u = 0; u < 2; ++u)
#pragma unroll
                for (int r = 0; r < 4; ++r) {
                    const float gi = acc[rt][0 + u][r];
                    const float gf = acc[rt][2 + u][r];
                    const float gg = acc[rt][4 + u][r];
                    const float go = acc[rt][6 + u][r];
                    const float cc = sigm(gf) * cst[rt][u][r] + sigm(gi) * tanh_f(gg);
                    cst[rt][u][r] = cc;
                    const float hh = sigm(go) * tanh_f(cc);
                    const int row = rt * 16 + q * 4 + r;
                    const int j   = w * 32 + u * 16 + m;
                    AHm[row * AHP + j] = (_Float16)hh;
                    yout[(size_t)(rb + row) * 15360 + t * 256 + dir * H_ + j] = (_Float16)hh;
                }
    }
}

// ---------------------------------------------------------------------------
// Final: out[b][o] = b_out[o] + sum relu(y3[b][:]) * w_out[o][:]
// One wave per batch row; 30 iters x half8 per lane.
// ---------------------------------------------------------------------------
__global__ __launch_bounds__(256)
void final_kernel(const _Float16* __restrict__ y, const float* __restrict__ wout,
                  const float* __restrict__ bout, float* __restrict__ outp, int nrows) {
    const int wid  = (blockIdx.x * blockDim.x + threadIdx.x) >> 6;
    const int lane = threadIdx.x & 63;
    if (wid >= nrows) return;
    const half8*  __restrict__ y8 = (const half8*)(y + (size_t)wid * 15360);
    const float4* __restrict__ w4 = (const float4*)wout;   // [2][3840]
    float s0 = 0.f, s1 = 0.f;
#pragma unroll 2
    for (int it = 0; it < 30; ++it) {
        const int idx = it * 64 + lane;
        half8 h = y8[idx];
        float v[8];
#pragma unroll
        for (int e = 0; e < 8; ++e) v[e] = fmaxf((float)h[e], 0.f);
        const float4 a0 = w4[idx * 2], a1 = w4[idx * 2 + 1];
        const float4 b0 = w4[3840 + idx * 2], b1 = w4[3840 + idx * 2 + 1];
        s0 += v[0] * a0.x + v[1] * a0.y + v[2] * a0.z + v[3] * a0.w
            + v[4] * a1.x + v[5] * a1.y + v[6] * a1.z + v[7] * a1.w;
        s1 += v[0] * b0.x + v[1] * b0.y + v[2] * b0.z + v[3] * b0.w
            + v[4] * b1.x + v[5] * b1.y + v[6] * b1.z + v[7] * b1.w;
    }
#pragma unroll
    for (int off = 32; off > 0; off >>= 1) {
        s0 += __shfl_down(s0, off);
        s1 += __shfl_down(s1, off);
    }
    if (lane == 0) {
        outp[wid * 2 + 0] = s0 + bout[0];
        outp[wid * 2 + 1] = s1 + bout[1];
    }
}

// ---------------------------------------------------------------------------
extern "C" void kernel_launch(void* const* d_in, const int* in_sizes, int n_in,
                              void* d_out, int out_size, void* d_ws, size_t ws_size,
                              hipStream_t stream) {
    const float* x = (const float*)d_in[0];
    auto W = [&](int l, int d, int which) { return (const float*)d_in[1 + l * 8 + d * 4 + which]; };
    const float* w_out = (const float*)d_in[25];
    const float* b_out = (const float*)d_in[26];

    // Workspace layout (halfs for packs, then fp32 bias, then fp16 y buffers).
    _Float16* wsH = (_Float16*)d_ws;
    // pack offsets (halfs): per (layer,dir): x-pack (KXT*16384) then h-pack (65536)
    const size_t px0f = 0,       ph0f = 16384;
    const size_t px0b = 81920,   ph0b = 98304;
    const size_t px1f = 163840,  ph1f = 294912;
    const size_t px1b = 360448,  ph1b = 491520;
    const size_t px2f = 557056,  ph2f = 688128;
    const size_t px2b = 753664,  ph2b = 884736;
    const size_t packs_end = 950272;              // halfs
    float* bias = (float*)(wsH + packs_end);      // 6*512 fp32
    const size_t head_bytes = packs_end * 2 + 3072 * 4;   // 1912832, 16B-aligned
    _Float16* y0 = (_Float16*)((char*)d_ws + head_bytes);

    // Allow >64KB dynamic LDS for the persistent kernels.
    hipFuncSetAttribute((const void*)lstm_mfma<1, 1>, hipFuncAttributeMaxDynamicSharedMemorySize, SMEM_BYTES);
    hipFuncSetAttribute((const void*)lstm_mfma<8, 0>, hipFuncAttributeMaxDynamicSharedMemorySize, SMEM_BYTES);

    // ---- weight packing (+ bias combine on the x-pack launches) ----
    pack_kernel<<<64, 256, 0, stream>>>(W(0,0,0), wsH + px0f, I_,  16384,  W(0,0,2), W(0,0,3), bias + 0);
    pack_kernel<<<256,256, 0, stream>>>(W(0,0,1), wsH + ph0f, H_,  65536,  nullptr, nullptr, nullptr);
    pack_kernel<<<64, 256, 0, stream>>>(W(0,1,0), wsH + px0b, I_,  16384,  W(0,1,2), W(0,1,3), bias + 512);
    pack_kernel<<<256,256, 0, stream>>>(W(0,1,1), wsH + ph0b, H_,  65536,  nullptr, nullptr, nullptr);
    pack_kernel<<<512,256, 0, stream>>>(W(1,0,0), wsH + px1f, 256, 131072, W(1,0,2), W(1,0,3), bias + 1024);
    pack_kernel<<<256,256, 0, stream>>>(W(1,0,1), wsH + ph1f, H_,  65536,  nullptr, nullptr, nullptr);
    pack_kernel<<<512,256, 0, stream>>>(W(1,1,0), wsH + px1b, 256, 131072, W(1,1,2), W(1,1,3), bias + 1536);
    pack_kernel<<<256,256, 0, stream>>>(W(1,1,1), wsH + ph1b, H_,  65536,  nullptr, nullptr, nullptr);
    pack_kernel<<<512,256, 0, stream>>>(W(2,0,0), wsH + px2f, 256, 131072, W(2,0,2), W(2,0,3), bias + 2048);
    pack_kernel<<<256,256, 0, stream>>>(W(2,0,1), wsH + ph2f, H_,  65536,  nullptr, nullptr, nullptr);
    pack_kernel<<<512,256, 0, stream>>>(W(2,1,0), wsH + px2b, 256, 131072, W(2,1,2), W(2,1,3), bias + 2560);
    pack_kernel<<<256,256, 0, stream>>>(W(2,1,1), wsH + ph2b, H_,  65536,  nullptr, nullptr, nullptr);

    // ---- pick batch chunking so 2 fp16 y-buffers fit in remaining ws ----
    const size_t avail_halfs = (ws_size > head_bytes) ? (ws_size - head_bytes) / 2 : 0;
    int chunks = 1;
    while (chunks < 128 && (size_t)2 * (B_ / chunks) * 15360 > avail_halfs) chunks *= 2;
    const int CB = B_ / chunks;

    _Float16* yA = y0;
    _Float16* yB = y0 + (size_t)CB * 15360;

    for (int c = 0; c < chunks; ++c) {
        const float* xc = x + (size_t)c * CB * (L_ * I_);
        float* outc = (float*)d_out + (size_t)c * CB * 2;
        lstm_mfma<1, 1><<<2 * CB / 32, 256, SMEM_BYTES, stream>>>(
            xc, nullptr, wsH + px0f, wsH + ph0f, wsH + px0b, wsH + ph0b, bias + 0, bias + 512, yA);
        lstm_mfma<8, 0><<<2 * CB / 32, 256, SMEM_BYTES, stream>>>(
            nullptr, yA, wsH + px1f, wsH + ph1f, wsH + px1b, wsH + ph1b, bias + 1024, bias + 1536, yB);
        lstm_mfma<8, 0><<<2 * CB / 32, 256, SMEM_BYTES, stream>>>(
            nullptr, yB, wsH + px2f, wsH + ph2f, wsH + px2b, wsH + ph2b, bias + 2048, bias + 2560, yA);
        final_kernel<<<(CB + 3) / 4, 256, 0, stream>>>(yA, w_out, b_out, outc, CB);
    }
}